// Round 1
// baseline (3367.461 us; speedup 1.0000x reference)
//
#include <hip/hip_runtime.h>
#include <hip/hip_bf16.h>
#include <hip/hip_fp16.h>

#define N_NODES 50000
#define N_EDGES 800000
#define NNIN    128
#define NOPEN   64
#define NUM_OUT 40
#define NLAYER  8
#define H2      0.01f

#define NDIG  ((N_NODES + 255) >> 8)          // 196 digits (node>>8)
#define EPB   2048                            // edges per pass1/count block
#define P1B   ((N_EDGES + EPB - 1) / EPB)     // 391 blocks
#define P2CAP 9216                            // mean 8163, sigma ~90 -> +11.7 sigma
#define SEGN  (N_NODES / 8)                   // 6250 nodes per work-queue segment

typedef float f32x2 __attribute__((ext_vector_type(2)));

__device__ __forceinline__ f32x2 pk_fma(f32x2 a, f32x2 b, f32x2 c) {
    f32x2 d;
    asm("v_pk_fma_f32 %0, %1, %2, %3" : "=v"(d) : "v"(a), "v"(b), "v"(c));
    return d;
}
__device__ __forceinline__ f32x2 pk_mul(f32x2 a, f32x2 b) {
    f32x2 d;
    asm("v_pk_mul_f32 %0, %1, %2" : "=v"(d) : "v"(a), "v"(b));
    return d;
}
__device__ __forceinline__ f32x2 h2f(__half2 h) {
    float2 f = __half22float2(h);
    return (f32x2){f.x, f.y};
}

// ---- prep ---------------------------------------------------------------

__global__ void deg_init(int* __restrict__ degi, int* __restrict__ ctrs) {
    int n = blockIdx.x * 256 + threadIdx.x;
    if (n < N_NODES) degi[n] = 1;   // self-loop (norm degree)
    if (blockIdx.x == 0 && threadIdx.x < 64) ctrs[threadIdx.x] = 0;  // 8 layers x 8 segs
}

// per-block LDS digit histogram + degi atomics (16/addr avg — safe);
// flush as DENSE writes to bh[b][NDIG]; zero global atomics for the hist.
__global__ __launch_bounds__(256) void count_all(const int* __restrict__ I,
                                                 const int* __restrict__ J,
                                                 int* __restrict__ degi,
                                                 int* __restrict__ bh) {
    __shared__ int h[NDIG];
    int t = threadIdx.x, b = blockIdx.x;
    for (int i = t; i < NDIG; i += 256) h[i] = 0;
    __syncthreads();
    int e0 = b * EPB;
    int e1 = min(e0 + EPB, N_EDGES);
    for (int e = e0 + t; e < e1; e += 256) {
        int i = I[e], j = J[e];
        atomicAdd(&degi[j], 1);
        atomicAdd(&h[i >> 8], 1);
        atomicAdd(&h[j >> 8], 1);
    }
    __syncthreads();
    for (int i = t; i < NDIG; i += 256) bh[b * NDIG + i] = h[i];
}

__global__ void calc_dinv(const int* __restrict__ degi, float* __restrict__ dinv) {
    int n = blockIdx.x * 256 + threadIdx.x;
    if (n < N_NODES) dinv[n] = rsqrtf((float)degi[n]);
}

// per-digit exclusive scan over blocks: off[d][b], total[d]. No atomics.
__global__ __launch_bounds__(512) void col_scan(const int* __restrict__ bh,
                                                int* __restrict__ off,
                                                int* __restrict__ total) {
    __shared__ int sh[512];
    int d = blockIdx.x, t = threadIdx.x;
    int v = (t < P1B) ? bh[t * NDIG + d] : 0;
    sh[t] = v;
    __syncthreads();
#pragma unroll
    for (int o = 1; o < 512; o <<= 1) {
        int x = (t >= o) ? sh[t - o] : 0;
        __syncthreads();
        sh[t] += x;
        __syncthreads();
    }
    if (t < P1B) off[d * P1B + t] = sh[t] - v;   // exclusive
    if (t == 511) total[d] = sh[511];
}

// digit-level scans: raw offsets (ebuf) and padded-capacity offsets (ent).
__global__ __launch_bounds__(256) void dig_scan(const int* __restrict__ total,
                                                int* __restrict__ dig_raw,
                                                int* __restrict__ dig_pad) {
    __shared__ int sh[256], sh2[256];
    int t = threadIdx.x;
    int v   = (t < NDIG) ? total[t] : 0;
    int cap = (t < NDIG) ? ((v + 768 + 3) & ~3) : 0;  // <=256 rows * 3 pad, x4 align
    sh[t] = v; sh2[t] = cap;
    __syncthreads();
#pragma unroll
    for (int o = 1; o < 256; o <<= 1) {
        int x = (t >= o) ? sh[t - o] : 0;
        int y = (t >= o) ? sh2[t - o] : 0;
        __syncthreads();
        sh[t] += x; sh2[t] += y;
        __syncthreads();
    }
    if (t < NDIG) { dig_raw[t] = sh[t] - v; dig_pad[t] = sh2[t] - cap; }
}

// pass 1: scatter packed (node<<16)|other into per-(block,digit) runs at
// PRECOMPUTED offsets — LDS atomics only; runs are block-owned => dense L2 WB.
__global__ __launch_bounds__(256) void pass1_scatter(const int* __restrict__ I,
                                                     const int* __restrict__ J,
                                                     const int* __restrict__ off,
                                                     const int* __restrict__ dig_raw,
                                                     unsigned* __restrict__ ebuf) {
    __shared__ int cnt2[NDIG];
    __shared__ int base[NDIG];
    int t = threadIdx.x, b = blockIdx.x;
    for (int i = t; i < NDIG; i += 256) {
        cnt2[i] = 0;
        base[i] = dig_raw[i] + off[i * P1B + b];
    }
    __syncthreads();
    int e0 = b * EPB;
    int e1 = min(e0 + EPB, N_EDGES);
    for (int e = e0 + t; e < e1; e += 256) {
        int i = I[e], j = J[e];
        int li = atomicAdd(&cnt2[i >> 8], 1);
        ebuf[base[i >> 8] + li] = ((unsigned)i << 16) | (unsigned)j;
        int lj = atomicAdd(&cnt2[j >> 8], 1);
        ebuf[base[j >> 8] + lj] = ((unsigned)j << 16) | (unsigned)i;
    }
}

// pass 2: one block per digit — LDS counting sort over the digit's 256 nodes;
// emits row_start, deg2, and padded CSR entries (other, w) as int2 pairs,
// w = dinv[n]*dinv[other] precomputed; pad entries get w=0 (exactly zero contrib).
__global__ __launch_bounds__(256) void pass2_csr(const unsigned* __restrict__ ebuf,
                                                 const int* __restrict__ dig_raw,
                                                 const int* __restrict__ total,
                                                 const int* __restrict__ dig_pad,
                                                 const float* __restrict__ dinv,
                                                 int* __restrict__ row_start,
                                                 int* __restrict__ deg2,
                                                 int2* __restrict__ ent) {
    __shared__ unsigned eb[P2CAP];
    __shared__ int cnt[256], loc[256], cur[256];
    int d = blockIdx.x, t = threadIdx.x;
    int s = dig_raw[d];
    int c = total[d]; if (c > P2CAP) c = P2CAP;   // 11.7-sigma guard
    for (int i = t; i < c; i += 256) eb[i] = ebuf[s + i];
    cnt[t] = 0;
    __syncthreads();
    for (int i = t; i < c; i += 256)
        atomicAdd(&cnt[(eb[i] >> 16) & 255], 1);
    __syncthreads();
    int pc = (cnt[t] + 3) & ~3;                   // padded row size (entries)
    loc[t] = pc;
    __syncthreads();
#pragma unroll
    for (int o = 1; o < 256; o <<= 1) {
        int x = (t >= o) ? loc[t - o] : 0;
        __syncthreads();
        loc[t] += x;
        __syncthreads();
    }
    int mybase = dig_pad[d] + loc[t] - pc;        // x4-aligned entry index
    int n = (d << 8) + t;
    if (n < N_NODES) {
        row_start[n] = mybase;
        deg2[n] = cnt[t];
    }
    cur[t] = mybase;
    __syncthreads();
    for (int i = t; i < c; i += 256) {
        unsigned v = eb[i];
        int ln = (int)(v >> 16) & 255;
        int other = (int)(v & 0xffffu);
        int p = atomicAdd(&cur[ln], 1);
        float w = dinv[(d << 8) + ln] * dinv[other];
        ent[p] = make_int2(other, __float_as_int(w));
    }
    __syncthreads();
    if (n < N_NODES) {
        for (int p = mybase + cnt[t]; p < mybase + pc; p++)
            ent[p] = make_int2(n, 0);              // w=0 pad: contributes 0
    }
}

// ---- first layer: x = relu(K1 @ xn_in), xn_in is (128, N) f32 ----------
__global__ __launch_bounds__(256) void first_layer(const float* __restrict__ xn,
                                                   const float* __restrict__ k1f,
                                                   float* __restrict__ x_cur,
                                                   float* __restrict__ x_old) {
    __shared__ float Ks[NOPEN * 129];
    __shared__ float xs[32 * 64];
    int t = threadIdx.x;
    int n0 = blockIdx.x * 64;
    for (int idx = t; idx < NOPEN * NNIN; idx += 256)
        Ks[(idx >> 7) * 129 + (idx & 127)] = k1f[idx];

    int tn = t & 15, to = t >> 4;
    float acc[4][4] = {};
    for (int c0 = 0; c0 < NNIN; c0 += 32) {
        __syncthreads();
        for (int idx = t; idx < 32 * 64; idx += 256) {
            int ci = idx >> 6, n = idx & 63;
            int gn = n0 + n;
            xs[ci * 64 + n] = (gn < N_NODES) ? xn[(size_t)(c0 + ci) * N_NODES + gn] : 0.f;
        }
        __syncthreads();
        for (int ci = 0; ci < 32; ci++) {
            float xv[4], kv[4];
#pragma unroll
            for (int i2 = 0; i2 < 4; i2++) xv[i2] = xs[ci * 64 + tn * 4 + i2];
#pragma unroll
            for (int j = 0; j < 4; j++) kv[j] = Ks[(to * 4 + j) * 129 + c0 + ci];
#pragma unroll
            for (int i2 = 0; i2 < 4; i2++)
#pragma unroll
                for (int j = 0; j < 4; j++) acc[i2][j] += xv[i2] * kv[j];
        }
    }
#pragma unroll
    for (int i2 = 0; i2 < 4; i2++) {
        int node = n0 + tn * 4 + i2;
        if (node < N_NODES) {
            float4 st;
            st.x = fmaxf(acc[i2][0], 0.f);
            st.y = fmaxf(acc[i2][1], 0.f);
            st.z = fmaxf(acc[i2][2], 0.f);
            st.w = fmaxf(acc[i2][3], 0.f);
            *(float4*)&x_cur[(size_t)node * 64 + to * 4] = st;
            *(float4*)&x_old[(size_t)node * 64 + to * 4] = st;
        }
    }
}

// ---- Y[n][o] = sum_c K[o][c] * x[n][c], fp16 out (layer 0 only) --------
__global__ __launch_bounds__(256) void mat_y(const float* __restrict__ x,
                                             const float* __restrict__ K,
                                             __half* __restrict__ Y) {
    __shared__ float Ks[64 * 65];
    __shared__ float xs[64 * 65];
    int t = threadIdx.x, n0 = blockIdx.x * 64;
    for (int idx = t; idx < 4096; idx += 256) {
        int r = idx >> 6, c = idx & 63;
        Ks[r * 65 + c] = K[idx];
        int gn = n0 + r;
        xs[r * 65 + c] = (gn < N_NODES) ? x[(size_t)gn * 64 + c] : 0.f;
    }
    __syncthreads();
    int tn = t & 15, to = t >> 4;
    float acc[4][4] = {};
    for (int c = 0; c < 64; c++) {
        float xv[4], kv[4];
#pragma unroll
        for (int i2 = 0; i2 < 4; i2++) xv[i2] = xs[(tn * 4 + i2) * 65 + c];
#pragma unroll
        for (int j = 0; j < 4; j++) kv[j] = Ks[(to * 4 + j) * 65 + c];
#pragma unroll
        for (int i2 = 0; i2 < 4; i2++)
#pragma unroll
            for (int j = 0; j < 4; j++) acc[i2][j] += xv[i2] * kv[j];
    }
#pragma unroll
    for (int i2 = 0; i2 < 4; i2++) {
        int node = n0 + tn * 4 + i2;
        if (node < N_NODES) {
            __half2 h0 = __floats2half2_rn(acc[i2][0], acc[i2][1]);
            __half2 h1 = __floats2half2_rn(acc[i2][2], acc[i2][3]);
            __half2* dst = (__half2*)&Y[(size_t)node * 64 + to * 4];
            dst[0] = h0;
            dst[1] = h1;
        }
    }
}

// ---- fused gather + update + next-layer Y --------------------------------
// Persistent waves + segmented atomic work queue (removes max-of-16 degree
// imbalance); packed-f32 poly tanh (no transcendentals); (other,w) CSR pairs
// (no dinv gathers); stride-66 LDS K tiles -> conflict-free b64 pk epilogue.
__global__ __launch_bounds__(1024) void gather_update(const __half* __restrict__ Y,
                                                      const float* __restrict__ x_cur,
                                                      const float* __restrict__ x_old,
                                                      const int2* __restrict__ ent,
                                                      const int* __restrict__ row_start,
                                                      const int* __restrict__ deg2,
                                                      const float* __restrict__ K,
                                                      const float* __restrict__ Kn,
                                                      float* __restrict__ x_out,
                                                      __half* __restrict__ Y_out,
                                                      int* __restrict__ ctr) {
    __shared__ float Ks[64 * 66];    // d[c] = sum_o K[c][o] s[o]   at Ks[c*66+o]
    __shared__ float Ksn[64 * 66];   // Y[o] = sum_c Kn[o][c] x[c]  at Ksn[o*66+c]
    __shared__ float Ss[16][64];
    int t = threadIdx.x;
    for (int idx = t; idx < 4096; idx += 1024) {
        int r = idx >> 6, cc = idx & 63;
        Ks[r * 66 + cc]  = K[idx];
        Ksn[r * 66 + cc] = Kn[idx];
    }
    __syncthreads();                 // one-time staging; no barriers in the loop

    int wv = t >> 6, lane = t & 63;
    int c2  = lane & 31;             // channel-pair index
    int sel = lane >> 5;             // 0: even entries, 1: odd entries

    // tanh(z) ~= z*(1 + z2*(C3 + z2*(C5 + z2*C7))); |z| <~ 0.1 here -> err < 1e-11
    const f32x2 C3v  = {-0.33333334f,  -0.33333334f };
    const f32x2 C5v  = { 0.13333334f,   0.13333334f };
    const f32x2 C7v  = {-0.053968254f, -0.053968254f};
    const f32x2 ONEv = { 1.0f, 1.0f };
    const f32x2 NEG1 = {-1.0f, -1.0f};

    int seg  = blockIdx.x & 7;       // segment == XCD round-robin slot (L2 affinity)
    int base = seg * SEGN;
    int lim  = base + SEGN;
    int* mc  = ctr + seg;

    for (;;) {
        int nn;
        if (lane == 0) nn = atomicAdd(mc, 2);
        nn = base + __shfl(nn, 0, 64);
        if (nn >= lim) break;
        int ne = min(nn + 2, lim);
        for (int n = nn; n < ne; n++) {
            f32x2 yn = h2f(*(const __half2*)&Y[((size_t)n << 6) + 2 * c2]);
            float xc = x_cur[(size_t)n * 64 + lane];
            float xo = x_old[(size_t)n * 64 + lane];
            int beg = __builtin_amdgcn_readfirstlane(row_start[n]);  // % 4 == 0
            int dg  = __builtin_amdgcn_readfirstlane(deg2[n]);
            int end = beg + ((dg + 3) & ~3);                         // padded, no tail
            f32x2 s = {0.f, 0.f};
            for (int k = beg; k < end; k += 4) {
                int4 A = *(const int4*)(ent + k);        // (o0,w0,o1,w1)
                int4 B = *(const int4*)(ent + k + 2);    // (o2,w2,o3,w3)
                int   oa = sel ? A.z : A.x;
                float wa = __int_as_float(sel ? A.w : A.y);
                int   ob = sel ? B.z : B.x;
                float wb = __int_as_float(sel ? B.w : B.y);
                f32x2 av = h2f(*(const __half2*)&Y[((size_t)(unsigned)oa << 6) + 2 * c2]);
                f32x2 bv = h2f(*(const __half2*)&Y[((size_t)(unsigned)ob << 6) + 2 * c2]);
                f32x2 wav = {wa, wa}, wbv = {wb, wb};
                f32x2 da  = pk_fma(av, NEG1, yn);        // yn - a
                f32x2 db  = pk_fma(bv, NEG1, yn);
                f32x2 za  = pk_mul(wav, da);
                f32x2 zb  = pk_mul(wbv, db);
                f32x2 za2 = pk_mul(za, za);
                f32x2 zb2 = pk_mul(zb, zb);
                f32x2 pa  = pk_fma(za2, pk_fma(za2, pk_fma(za2, C7v, C5v), C3v), ONEv);
                f32x2 pb  = pk_fma(zb2, pk_fma(zb2, pk_fma(zb2, C7v, C5v), C3v), ONEv);
                s = pk_fma(pk_mul(wav, za), pa, s);      // += w * tanh(w*(yn-a))
                s = pk_fma(pk_mul(wbv, zb), pb, s);
            }
            s.x += __shfl_xor(s.x, 32, 64);
            s.y += __shfl_xor(s.y, 32, 64);
            if (lane < 32) *(f32x2*)&Ss[wv][2 * c2] = s;   // in-wave LDS ordering
            f32x2 acc2 = {0.f, 0.f};
#pragma unroll
            for (int o = 0; o < 64; o += 2)
                acc2 = pk_fma(*(const f32x2*)&Ks[lane * 66 + o],
                              *(const f32x2*)&Ss[wv][o], acc2);
            float xnew = 2.f * xc - xo - H2 * (acc2.x + acc2.y);
            __builtin_nontemporal_store(xnew, &x_out[(size_t)n * 64 + lane]);
            Ss[wv][lane] = xnew;
            f32x2 acc3 = {0.f, 0.f};
#pragma unroll
            for (int c = 0; c < 64; c += 2)
                acc3 = pk_fma(*(const f32x2*)&Ksn[lane * 66 + c],
                              *(const f32x2*)&Ss[wv][c], acc3);
            Y_out[((size_t)n << 6) + lane] = __float2half(acc3.x + acc3.y);
        }
    }
}

// ---- out[n][o] = sum_c KNc[o][c] * x[n][c]; out is (N,40) f32 ----------
__global__ __launch_bounds__(256) void out_kernel(const float* __restrict__ x,
                                                  const float* __restrict__ Kc,
                                                  float* __restrict__ out) {
    __shared__ float xs[64 * 65];
    __shared__ float Ks[40 * 65];
    int t = threadIdx.x, n0 = blockIdx.x * 64;
    for (int idx = t; idx < 4096; idx += 256) {
        int r = idx >> 6, c = idx & 63;
        int gn = n0 + r;
        xs[r * 65 + c] = (gn < N_NODES) ? x[(size_t)gn * 64 + c] : 0.f;
    }
    for (int idx = t; idx < NUM_OUT * 64; idx += 256) {
        int r = idx >> 6, c = idx & 63;
        Ks[r * 65 + c] = Kc[idx];
    }
    __syncthreads();
    if (t < 160) {
        int tn = t & 15, to = t >> 4;
        float acc[4][4] = {};
        for (int c = 0; c < 64; c++) {
            float xv[4], kv[4];
#pragma unroll
            for (int i2 = 0; i2 < 4; i2++) xv[i2] = xs[(tn * 4 + i2) * 65 + c];
#pragma unroll
            for (int j = 0; j < 4; j++) kv[j] = Ks[(to * 4 + j) * 65 + c];
#pragma unroll
            for (int i2 = 0; i2 < 4; i2++)
#pragma unroll
                for (int j = 0; j < 4; j++) acc[i2][j] += xv[i2] * kv[j];
        }
#pragma unroll
        for (int i2 = 0; i2 < 4; i2++) {
            int node = n0 + tn * 4 + i2;
            if (node < N_NODES) {
#pragma unroll
                for (int j = 0; j < 4; j++)
                    out[(size_t)node * NUM_OUT + to * 4 + j] = acc[i2][j];
            }
        }
    }
}

extern "C" void kernel_launch(void* const* d_in, const int* in_sizes, int n_in,
                              void* d_out, int out_size, void* d_ws, size_t ws_size,
                              hipStream_t stream) {
    const float* xn = (const float*)d_in[0];
    const int*   I  = (const int*)d_in[1];
    const int*   J  = (const int*)d_in[2];
    const float* K1 = (const float*)d_in[4];
    const float* K2 = (const float*)d_in[5];
    const float* Kc = (const float*)d_in[6];

    const size_t NC = (size_t)N_NODES * NOPEN;  // 3.2M
    float*    f       = (float*)d_ws;
    float*    x_cur   = f;
    float*    x_old   = f + NC;
    __half*   Y0      = (__half*)(f + 2 * NC);
    __half*   Y1      = (__half*)(f + 2 * NC + NC / 2);
    float*    dinv    = f + 3 * NC;
    int*      degi    = (int*)(dinv + N_NODES);
    int*      deg2    = degi + N_NODES;
    int*      row_st  = deg2 + N_NODES;
    int*      total   = row_st + N_NODES;          // 256
    int*      dig_raw = total + 256;               // 256
    int*      dig_pad = dig_raw + 256;             // 256
    int*      ctrs    = dig_pad + 256;             // 64 (8 layers x 8 segments)
    int*      bh      = ctrs + 64;                 // P1B*NDIG = 76636
    int*      off     = bh + 80000;                // NDIG*P1B = 76636
    unsigned* ebuf    = (unsigned*)(off + 80000);  // 1.6M u32
    int2*     ent     = (int2*)(ebuf + 2 * (size_t)N_EDGES);  // ~1.76M int2 (14MB)

    dim3 B(256);
    const int GN = (N_NODES + 255) / 256;   // 196

    deg_init<<<GN, B, 0, stream>>>(degi, ctrs);
    count_all<<<P1B, B, 0, stream>>>(I, J, degi, bh);
    calc_dinv<<<GN, B, 0, stream>>>(degi, dinv);
    col_scan<<<NDIG, dim3(512), 0, stream>>>(bh, off, total);
    dig_scan<<<1, B, 0, stream>>>(total, dig_raw, dig_pad);
    pass1_scatter<<<P1B, B, 0, stream>>>(I, J, off, dig_raw, ebuf);
    pass2_csr<<<NDIG, B, 0, stream>>>(ebuf, dig_raw, total, dig_pad, dinv, row_st, deg2, ent);

    const int NB = (N_NODES + 63) / 64;     // 782
    first_layer<<<NB, B, 0, stream>>>(xn, K1, x_cur, x_old);
    mat_y<<<NB, B, 0, stream>>>(x_cur, K2, Y0);   // Y for layer 0 only

    __half* Yin = Y0;
    __half* Yout = Y1;
    float* xc = x_cur;
    float* xo = x_old;
    for (int l = 0; l < NLAYER; l++) {
        const float* Kl = K2 + l * NOPEN * NOPEN;
        const float* Knext = K2 + (l + 1 < NLAYER ? l + 1 : l) * NOPEN * NOPEN;
        gather_update<<<512, dim3(1024), 0, stream>>>(
            Yin, xc, xo, ent, row_st, deg2, Kl, Knext, xo, Yout, ctrs + l * 8);
        float* tmp = xc; xc = xo; xo = tmp;
        __half* th = Yin; Yin = Yout; Yout = th;
    }
    out_kernel<<<NB, B, 0, stream>>>(xc, Kc, (float*)d_out);
}

// Round 2
// 733.892 us; speedup vs baseline: 4.5885x; 4.5885x over previous
//
#include <hip/hip_runtime.h>
#include <hip/hip_bf16.h>
#include <hip/hip_fp16.h>

#define N_NODES 50000
#define N_EDGES 800000
#define NNIN    128
#define NOPEN   64
#define NUM_OUT 40
#define NLAYER  8
#define H2      0.01f

#define NDIG  ((N_NODES + 255) >> 8)          // 196 digits (node>>8)
#define EPB   2048                            // edges per pass1/count block
#define P1B   ((N_EDGES + EPB - 1) / EPB)     // 391 blocks
#define P2CAP 9216                            // mean 8163, sigma ~90 -> +11.7 sigma

typedef float f32x2 __attribute__((ext_vector_type(2)));

__device__ __forceinline__ f32x2 pk_fma(f32x2 a, f32x2 b, f32x2 c) {
    f32x2 d;
    asm("v_pk_fma_f32 %0, %1, %2, %3" : "=v"(d) : "v"(a), "v"(b), "v"(c));
    return d;
}
__device__ __forceinline__ f32x2 pk_mul(f32x2 a, f32x2 b) {
    f32x2 d;
    asm("v_pk_mul_f32 %0, %1, %2" : "=v"(d) : "v"(a), "v"(b));
    return d;
}
__device__ __forceinline__ f32x2 h2f(__half2 h) {
    float2 f = __half22float2(h);
    return (f32x2){f.x, f.y};
}

// ---- prep ---------------------------------------------------------------

__global__ void deg_init(int* __restrict__ degi) {
    int n = blockIdx.x * 256 + threadIdx.x;
    if (n < N_NODES) degi[n] = 1;   // self-loop (norm degree)
}

// per-block LDS digit histogram + degi atomics (16/addr avg — safe);
// flush as DENSE writes to bh[b][NDIG]; zero global atomics for the hist.
__global__ __launch_bounds__(256) void count_all(const int* __restrict__ I,
                                                 const int* __restrict__ J,
                                                 int* __restrict__ degi,
                                                 int* __restrict__ bh) {
    __shared__ int h[NDIG];
    int t = threadIdx.x, b = blockIdx.x;
    for (int i = t; i < NDIG; i += 256) h[i] = 0;
    __syncthreads();
    int e0 = b * EPB;
    int e1 = min(e0 + EPB, N_EDGES);
    for (int e = e0 + t; e < e1; e += 256) {
        int i = I[e], j = J[e];
        atomicAdd(&degi[j], 1);
        atomicAdd(&h[i >> 8], 1);
        atomicAdd(&h[j >> 8], 1);
    }
    __syncthreads();
    for (int i = t; i < NDIG; i += 256) bh[b * NDIG + i] = h[i];
}

__global__ void calc_dinv(const int* __restrict__ degi, float* __restrict__ dinv) {
    int n = blockIdx.x * 256 + threadIdx.x;
    if (n < N_NODES) dinv[n] = rsqrtf((float)degi[n]);
}

// per-digit exclusive scan over blocks: off[d][b], total[d]. No atomics.
__global__ __launch_bounds__(512) void col_scan(const int* __restrict__ bh,
                                                int* __restrict__ off,
                                                int* __restrict__ total) {
    __shared__ int sh[512];
    int d = blockIdx.x, t = threadIdx.x;
    int v = (t < P1B) ? bh[t * NDIG + d] : 0;
    sh[t] = v;
    __syncthreads();
#pragma unroll
    for (int o = 1; o < 512; o <<= 1) {
        int x = (t >= o) ? sh[t - o] : 0;
        __syncthreads();
        sh[t] += x;
        __syncthreads();
    }
    if (t < P1B) off[d * P1B + t] = sh[t] - v;   // exclusive
    if (t == 511) total[d] = sh[511];
}

// digit-level scans: raw offsets (ebuf) and padded-capacity offsets (ent).
// Rows are padded to x8 now (8-entry unrolled gather loop).
__global__ __launch_bounds__(256) void dig_scan(const int* __restrict__ total,
                                                int* __restrict__ dig_raw,
                                                int* __restrict__ dig_pad) {
    __shared__ int sh[256], sh2[256];
    int t = threadIdx.x;
    int v   = (t < NDIG) ? total[t] : 0;
    int cap = (t < NDIG) ? ((v + 256 * 7 + 7) & ~7) : 0;  // <=256 rows * 7 pad, x8 align
    sh[t] = v; sh2[t] = cap;
    __syncthreads();
#pragma unroll
    for (int o = 1; o < 256; o <<= 1) {
        int x = (t >= o) ? sh[t - o] : 0;
        int y = (t >= o) ? sh2[t - o] : 0;
        __syncthreads();
        sh[t] += x; sh2[t] += y;
        __syncthreads();
    }
    if (t < NDIG) { dig_raw[t] = sh[t] - v; dig_pad[t] = sh2[t] - cap; }
}

// pass 1: scatter packed (node<<16)|other into per-(block,digit) runs at
// PRECOMPUTED offsets — LDS atomics only; runs are block-owned => dense L2 WB.
__global__ __launch_bounds__(256) void pass1_scatter(const int* __restrict__ I,
                                                     const int* __restrict__ J,
                                                     const int* __restrict__ off,
                                                     const int* __restrict__ dig_raw,
                                                     unsigned* __restrict__ ebuf) {
    __shared__ int cnt2[NDIG];
    __shared__ int base[NDIG];
    int t = threadIdx.x, b = blockIdx.x;
    for (int i = t; i < NDIG; i += 256) {
        cnt2[i] = 0;
        base[i] = dig_raw[i] + off[i * P1B + b];
    }
    __syncthreads();
    int e0 = b * EPB;
    int e1 = min(e0 + EPB, N_EDGES);
    for (int e = e0 + t; e < e1; e += 256) {
        int i = I[e], j = J[e];
        int li = atomicAdd(&cnt2[i >> 8], 1);
        ebuf[base[i >> 8] + li] = ((unsigned)i << 16) | (unsigned)j;
        int lj = atomicAdd(&cnt2[j >> 8], 1);
        ebuf[base[j >> 8] + lj] = ((unsigned)j << 16) | (unsigned)i;
    }
}

// pass 2: one block per digit — LDS counting sort over the digit's 256 nodes;
// emits row_start, deg2, and padded CSR entries (other, w) as int2 pairs,
// w = dinv[n]*dinv[other] precomputed; pad entries get w=0 (exactly zero contrib).
// Rows padded to x8.
__global__ __launch_bounds__(256) void pass2_csr(const unsigned* __restrict__ ebuf,
                                                 const int* __restrict__ dig_raw,
                                                 const int* __restrict__ total,
                                                 const int* __restrict__ dig_pad,
                                                 const float* __restrict__ dinv,
                                                 int* __restrict__ row_start,
                                                 int* __restrict__ deg2,
                                                 int2* __restrict__ ent) {
    __shared__ unsigned eb[P2CAP];
    __shared__ int cnt[256], loc[256], cur[256];
    int d = blockIdx.x, t = threadIdx.x;
    int s = dig_raw[d];
    int c = total[d]; if (c > P2CAP) c = P2CAP;   // 11.7-sigma guard
    for (int i = t; i < c; i += 256) eb[i] = ebuf[s + i];
    cnt[t] = 0;
    __syncthreads();
    for (int i = t; i < c; i += 256)
        atomicAdd(&cnt[(eb[i] >> 16) & 255], 1);
    __syncthreads();
    int pc = (cnt[t] + 7) & ~7;                   // padded row size (entries, x8)
    loc[t] = pc;
    __syncthreads();
#pragma unroll
    for (int o = 1; o < 256; o <<= 1) {
        int x = (t >= o) ? loc[t - o] : 0;
        __syncthreads();
        loc[t] += x;
        __syncthreads();
    }
    int mybase = dig_pad[d] + loc[t] - pc;        // x8-aligned entry index
    int n = (d << 8) + t;
    if (n < N_NODES) {
        row_start[n] = mybase;
        deg2[n] = cnt[t];
    }
    cur[t] = mybase;
    __syncthreads();
    for (int i = t; i < c; i += 256) {
        unsigned v = eb[i];
        int ln = (int)(v >> 16) & 255;
        int other = (int)(v & 0xffffu);
        int p = atomicAdd(&cur[ln], 1);
        float w = dinv[(d << 8) + ln] * dinv[other];
        ent[p] = make_int2(other, __float_as_int(w));
    }
    __syncthreads();
    if (n < N_NODES) {
        for (int p = mybase + cnt[t]; p < mybase + pc; p++)
            ent[p] = make_int2(n, 0);              // w=0 pad: contributes 0
    }
}

// ---- first layer: x = relu(K1 @ xn_in), xn_in is (128, N) f32 ----------
__global__ __launch_bounds__(256) void first_layer(const float* __restrict__ xn,
                                                   const float* __restrict__ k1f,
                                                   float* __restrict__ x_cur,
                                                   float* __restrict__ x_old) {
    __shared__ float Ks[NOPEN * 129];
    __shared__ float xs[32 * 64];
    int t = threadIdx.x;
    int n0 = blockIdx.x * 64;
    for (int idx = t; idx < NOPEN * NNIN; idx += 256)
        Ks[(idx >> 7) * 129 + (idx & 127)] = k1f[idx];

    int tn = t & 15, to = t >> 4;
    float acc[4][4] = {};
    for (int c0 = 0; c0 < NNIN; c0 += 32) {
        __syncthreads();
        for (int idx = t; idx < 32 * 64; idx += 256) {
            int ci = idx >> 6, n = idx & 63;
            int gn = n0 + n;
            xs[ci * 64 + n] = (gn < N_NODES) ? xn[(size_t)(c0 + ci) * N_NODES + gn] : 0.f;
        }
        __syncthreads();
        for (int ci = 0; ci < 32; ci++) {
            float xv[4], kv[4];
#pragma unroll
            for (int i2 = 0; i2 < 4; i2++) xv[i2] = xs[ci * 64 + tn * 4 + i2];
#pragma unroll
            for (int j = 0; j < 4; j++) kv[j] = Ks[(to * 4 + j) * 129 + c0 + ci];
#pragma unroll
            for (int i2 = 0; i2 < 4; i2++)
#pragma unroll
                for (int j = 0; j < 4; j++) acc[i2][j] += xv[i2] * kv[j];
        }
    }
#pragma unroll
    for (int i2 = 0; i2 < 4; i2++) {
        int node = n0 + tn * 4 + i2;
        if (node < N_NODES) {
            float4 st;
            st.x = fmaxf(acc[i2][0], 0.f);
            st.y = fmaxf(acc[i2][1], 0.f);
            st.z = fmaxf(acc[i2][2], 0.f);
            st.w = fmaxf(acc[i2][3], 0.f);
            *(float4*)&x_cur[(size_t)node * 64 + to * 4] = st;
            *(float4*)&x_old[(size_t)node * 64 + to * 4] = st;
        }
    }
}

// ---- Y[n][o] = sum_c K[o][c] * x[n][c], fp16 out (layer 0 only) --------
__global__ __launch_bounds__(256) void mat_y(const float* __restrict__ x,
                                             const float* __restrict__ K,
                                             __half* __restrict__ Y) {
    __shared__ float Ks[64 * 65];
    __shared__ float xs[64 * 65];
    int t = threadIdx.x, n0 = blockIdx.x * 64;
    for (int idx = t; idx < 4096; idx += 256) {
        int r = idx >> 6, c = idx & 63;
        Ks[r * 65 + c] = K[idx];
        int gn = n0 + r;
        xs[r * 65 + c] = (gn < N_NODES) ? x[(size_t)gn * 64 + c] : 0.f;
    }
    __syncthreads();
    int tn = t & 15, to = t >> 4;
    float acc[4][4] = {};
    for (int c = 0; c < 64; c++) {
        float xv[4], kv[4];
#pragma unroll
        for (int i2 = 0; i2 < 4; i2++) xv[i2] = xs[(tn * 4 + i2) * 65 + c];
#pragma unroll
        for (int j = 0; j < 4; j++) kv[j] = Ks[(to * 4 + j) * 65 + c];
#pragma unroll
        for (int i2 = 0; i2 < 4; i2++)
#pragma unroll
            for (int j = 0; j < 4; j++) acc[i2][j] += xv[i2] * kv[j];
    }
#pragma unroll
    for (int i2 = 0; i2 < 4; i2++) {
        int node = n0 + tn * 4 + i2;
        if (node < N_NODES) {
            __half2 h0 = __floats2half2_rn(acc[i2][0], acc[i2][1]);
            __half2 h1 = __floats2half2_rn(acc[i2][2], acc[i2][3]);
            __half2* dst = (__half2*)&Y[(size_t)node * 64 + to * 4];
            dst[0] = h0;
            dst[1] = h1;
        }
    }
}

// ---- fused gather + update + next-layer Y --------------------------------
// Static 1-node-per-wave (R0-proven structure; no atomics). Packed-f32 poly
// tanh; (other,w) CSR pairs; 8-entry unrolled gather loop (4 int4 + 4 gathers
// in flight); row meta prefetched under K staging; stride-66 conflict-free
// b64 pk epilogue. Grid covers exactly N_NODES -> no bounds checks.
__global__ __launch_bounds__(1024) void gather_update(const __half* __restrict__ Y,
                                                      const float* __restrict__ x_cur,
                                                      const float* __restrict__ x_old,
                                                      const int2* __restrict__ ent,
                                                      const int* __restrict__ row_start,
                                                      const int* __restrict__ deg2,
                                                      const float* __restrict__ K,
                                                      const float* __restrict__ Kn,
                                                      float* __restrict__ x_out,
                                                      __half* __restrict__ Y_out) {
    __shared__ float Ks[64 * 66];    // d[c] = sum_o K[c][o] s[o]   at Ks[c*66+o]
    __shared__ float Ksn[64 * 66];   // Y[o] = sum_c Kn[o][c] x[c]  at Ksn[o*66+c]
    __shared__ float Ss[16][64];
    int t = threadIdx.x;
    int wv = t >> 6, lane = t & 63;
    int c2  = lane & 31;             // channel-pair index
    int sel = lane >> 5;             // 0: even entries, 1: odd entries
    int n = blockIdx.x * 16 + wv;    // grid == N_NODES/16 exactly

    // issue per-node meta + state loads first: latency hides under K staging
    int beg = row_start[n];
    int dg  = deg2[n];
    f32x2 yn = h2f(*(const __half2*)&Y[((size_t)n << 6) + 2 * c2]);
    float xc = x_cur[(size_t)n * 64 + lane];
    float xo = x_old[(size_t)n * 64 + lane];

    for (int idx = t; idx < 4096; idx += 1024) {
        int r = idx >> 6, cc = idx & 63;
        Ks[r * 66 + cc]  = K[idx];
        Ksn[r * 66 + cc] = Kn[idx];
    }
    __syncthreads();

    beg = __builtin_amdgcn_readfirstlane(beg);   // % 8 == 0
    dg  = __builtin_amdgcn_readfirstlane(dg);
    int end = beg + ((dg + 7) & ~7);             // x8-padded, no tail

    // tanh(z) ~= z*(1 + z2*(C3 + z2*(C5 + z2*C7))); |z| <~ 0.1 here -> err < 1e-11
    const f32x2 C3v  = {-0.33333334f,  -0.33333334f };
    const f32x2 C5v  = { 0.13333334f,   0.13333334f };
    const f32x2 C7v  = {-0.053968254f, -0.053968254f};
    const f32x2 ONEv = { 1.0f, 1.0f };
    const f32x2 NEG1 = {-1.0f, -1.0f};

    f32x2 s = {0.f, 0.f};
    for (int k = beg; k < end; k += 8) {
        const int4 A = *(const int4*)(ent + k);        // (o0,w0,o1,w1)
        const int4 B = *(const int4*)(ent + k + 2);
        const int4 C = *(const int4*)(ent + k + 4);
        const int4 D = *(const int4*)(ent + k + 6);
        int   o0 = sel ? A.z : A.x;  float w0 = __int_as_float(sel ? A.w : A.y);
        int   o1 = sel ? B.z : B.x;  float w1 = __int_as_float(sel ? B.w : B.y);
        int   o2 = sel ? C.z : C.x;  float w2 = __int_as_float(sel ? C.w : C.y);
        int   o3 = sel ? D.z : D.x;  float w3 = __int_as_float(sel ? D.w : D.y);
        f32x2 g0 = h2f(*(const __half2*)&Y[((size_t)(unsigned)o0 << 6) + 2 * c2]);
        f32x2 g1 = h2f(*(const __half2*)&Y[((size_t)(unsigned)o1 << 6) + 2 * c2]);
        f32x2 g2 = h2f(*(const __half2*)&Y[((size_t)(unsigned)o2 << 6) + 2 * c2]);
        f32x2 g3 = h2f(*(const __half2*)&Y[((size_t)(unsigned)o3 << 6) + 2 * c2]);
#define EDGE_ACC(gv, wf)                                                    \
        {                                                                   \
            f32x2 wvv = {wf, wf};                                           \
            f32x2 dd  = pk_fma(gv, NEG1, yn);                               \
            f32x2 zz  = pk_mul(wvv, dd);                                    \
            f32x2 z2  = pk_mul(zz, zz);                                     \
            f32x2 pp  = pk_fma(z2, pk_fma(z2, pk_fma(z2, C7v, C5v), C3v), ONEv); \
            s = pk_fma(pk_mul(wvv, zz), pp, s);                             \
        }
        EDGE_ACC(g0, w0)
        EDGE_ACC(g1, w1)
        EDGE_ACC(g2, w2)
        EDGE_ACC(g3, w3)
#undef EDGE_ACC
    }
    s.x += __shfl_xor(s.x, 32, 64);
    s.y += __shfl_xor(s.y, 32, 64);
    if (lane < 32) *(f32x2*)&Ss[wv][2 * c2] = s;   // in-wave LDS ordering

    f32x2 acc2 = {0.f, 0.f};
#pragma unroll
    for (int o = 0; o < 64; o += 2)
        acc2 = pk_fma(*(const f32x2*)&Ks[lane * 66 + o],
                      *(const f32x2*)&Ss[wv][o], acc2);
    float xnew = 2.f * xc - xo - H2 * (acc2.x + acc2.y);
    __builtin_nontemporal_store(xnew, &x_out[(size_t)n * 64 + lane]);
    Ss[wv][lane] = xnew;
    f32x2 acc3 = {0.f, 0.f};
#pragma unroll
    for (int c = 0; c < 64; c += 2)
        acc3 = pk_fma(*(const f32x2*)&Ksn[lane * 66 + c],
                      *(const f32x2*)&Ss[wv][c], acc3);
    Y_out[((size_t)n << 6) + lane] = __float2half(acc3.x + acc3.y);
}

// ---- out[n][o] = sum_c KNc[o][c] * x[n][c]; out is (N,40) f32 ----------
__global__ __launch_bounds__(256) void out_kernel(const float* __restrict__ x,
                                                  const float* __restrict__ Kc,
                                                  float* __restrict__ out) {
    __shared__ float xs[64 * 65];
    __shared__ float Ks[40 * 65];
    int t = threadIdx.x, n0 = blockIdx.x * 64;
    for (int idx = t; idx < 4096; idx += 256) {
        int r = idx >> 6, c = idx & 63;
        int gn = n0 + r;
        xs[r * 65 + c] = (gn < N_NODES) ? x[(size_t)gn * 64 + c] : 0.f;
    }
    for (int idx = t; idx < NUM_OUT * 64; idx += 256) {
        int r = idx >> 6, c = idx & 63;
        Ks[r * 65 + c] = Kc[idx];
    }
    __syncthreads();
    if (t < 160) {
        int tn = t & 15, to = t >> 4;
        float acc[4][4] = {};
        for (int c = 0; c < 64; c++) {
            float xv[4], kv[4];
#pragma unroll
            for (int i2 = 0; i2 < 4; i2++) xv[i2] = xs[(tn * 4 + i2) * 65 + c];
#pragma unroll
            for (int j = 0; j < 4; j++) kv[j] = Ks[(to * 4 + j) * 65 + c];
#pragma unroll
            for (int i2 = 0; i2 < 4; i2++)
#pragma unroll
                for (int j = 0; j < 4; j++) acc[i2][j] += xv[i2] * kv[j];
        }
#pragma unroll
        for (int i2 = 0; i2 < 4; i2++) {
            int node = n0 + tn * 4 + i2;
            if (node < N_NODES) {
#pragma unroll
                for (int j = 0; j < 4; j++)
                    out[(size_t)node * NUM_OUT + to * 4 + j] = acc[i2][j];
            }
        }
    }
}

extern "C" void kernel_launch(void* const* d_in, const int* in_sizes, int n_in,
                              void* d_out, int out_size, void* d_ws, size_t ws_size,
                              hipStream_t stream) {
    const float* xn = (const float*)d_in[0];
    const int*   I  = (const int*)d_in[1];
    const int*   J  = (const int*)d_in[2];
    const float* K1 = (const float*)d_in[4];
    const float* K2 = (const float*)d_in[5];
    const float* Kc = (const float*)d_in[6];

    const size_t NC = (size_t)N_NODES * NOPEN;  // 3.2M
    float*    f       = (float*)d_ws;
    float*    x_cur   = f;
    float*    x_old   = f + NC;
    __half*   Y0      = (__half*)(f + 2 * NC);
    __half*   Y1      = (__half*)(f + 2 * NC + NC / 2);
    float*    dinv    = f + 3 * NC;
    int*      degi    = (int*)(dinv + N_NODES);
    int*      deg2    = degi + N_NODES;
    int*      row_st  = deg2 + N_NODES;
    int*      total   = row_st + N_NODES;          // 256
    int*      dig_raw = total + 256;               // 256
    int*      dig_pad = dig_raw + 256;             // 256
    int*      bh      = dig_pad + 256;             // P1B*NDIG = 76636
    int*      off     = bh + 80000;                // NDIG*P1B = 76636
    unsigned* ebuf    = (unsigned*)(off + 80000);  // 1.6M u32
    int2*     ent     = (int2*)(ebuf + 2 * (size_t)N_EDGES);  // ~1.96M int2 (~16MB)

    dim3 B(256);
    const int GN = (N_NODES + 255) / 256;   // 196

    deg_init<<<GN, B, 0, stream>>>(degi);
    count_all<<<P1B, B, 0, stream>>>(I, J, degi, bh);
    calc_dinv<<<GN, B, 0, stream>>>(degi, dinv);
    col_scan<<<NDIG, dim3(512), 0, stream>>>(bh, off, total);
    dig_scan<<<1, B, 0, stream>>>(total, dig_raw, dig_pad);
    pass1_scatter<<<P1B, B, 0, stream>>>(I, J, off, dig_raw, ebuf);
    pass2_csr<<<NDIG, B, 0, stream>>>(ebuf, dig_raw, total, dig_pad, dinv, row_st, deg2, ent);

    const int NB = (N_NODES + 63) / 64;     // 782
    first_layer<<<NB, B, 0, stream>>>(xn, K1, x_cur, x_old);
    mat_y<<<NB, B, 0, stream>>>(x_cur, K2, Y0);   // Y for layer 0 only

    __half* Yin = Y0;
    __half* Yout = Y1;
    float* xc = x_cur;
    float* xo = x_old;
    for (int l = 0; l < NLAYER; l++) {
        const float* Kl = K2 + l * NOPEN * NOPEN;
        const float* Knext = K2 + (l + 1 < NLAYER ? l + 1 : l) * NOPEN * NOPEN;
        gather_update<<<(N_NODES + 15) / 16, dim3(1024), 0, stream>>>(
            Yin, xc, xo, ent, row_st, deg2, Kl, Knext, xo, Yout);
        float* tmp = xc; xc = xo; xo = tmp;
        __half* th = Yin; Yin = Yout; Yout = th;
    }
    out_kernel<<<NB, B, 0, stream>>>(xc, Kc, (float*)d_out);
}

// Round 4
// 726.402 us; speedup vs baseline: 4.6358x; 1.0103x over previous
//
#include <hip/hip_runtime.h>
#include <hip/hip_bf16.h>
#include <hip/hip_fp16.h>

#define N_NODES 50000
#define N_EDGES 800000
#define NNIN    128
#define NOPEN   64
#define NUM_OUT 40
#define NLAYER  8
#define HSQ     0.01f

#define NDIG  ((N_NODES + 255) >> 8)          // 196 digits (node>>8) == node-block count
#define EPB   2048                            // edges per pass1/count block
#define P1B   ((N_EDGES + EPB - 1) / EPB)     // 391 blocks
#define P2CAP 9216                            // mean 8163, sigma ~90 -> +11.7 sigma
#define SBIN  32                              // degree-sort buckets (deg>>3)

typedef float f32x2 __attribute__((ext_vector_type(2)));

__device__ __forceinline__ f32x2 pk_fma(f32x2 a, f32x2 b, f32x2 c) {
    f32x2 d;
    asm("v_pk_fma_f32 %0, %1, %2, %3" : "=v"(d) : "v"(a), "v"(b), "v"(c));
    return d;
}
__device__ __forceinline__ f32x2 pk_mul(f32x2 a, f32x2 b) {
    f32x2 d;
    asm("v_pk_mul_f32 %0, %1, %2" : "=v"(d) : "v"(a), "v"(b));
    return d;
}
__device__ __forceinline__ f32x2 h2f(__half2 h) {
    float2 f = __half22float2(h);
    return (f32x2){f.x, f.y};
}

// ---- prep ---------------------------------------------------------------

__global__ void deg_init(int* __restrict__ degi) {
    int n = blockIdx.x * 256 + threadIdx.x;
    if (n < N_NODES) degi[n] = 1;   // self-loop (norm degree)
}

__global__ __launch_bounds__(256) void count_all(const int* __restrict__ I,
                                                 const int* __restrict__ J,
                                                 int* __restrict__ degi,
                                                 int* __restrict__ bh) {
    __shared__ int h[NDIG];
    int t = threadIdx.x, b = blockIdx.x;
    for (int i = t; i < NDIG; i += 256) h[i] = 0;
    __syncthreads();
    int e0 = b * EPB;
    int e1 = min(e0 + EPB, N_EDGES);
    for (int e = e0 + t; e < e1; e += 256) {
        int i = I[e], j = J[e];
        atomicAdd(&degi[j], 1);
        atomicAdd(&h[i >> 8], 1);
        atomicAdd(&h[j >> 8], 1);
    }
    __syncthreads();
    for (int i = t; i < NDIG; i += 256) bh[b * NDIG + i] = h[i];
}

__global__ void calc_dinv(const int* __restrict__ degi, float* __restrict__ dinv) {
    int n = blockIdx.x * 256 + threadIdx.x;
    if (n < N_NODES) dinv[n] = rsqrtf((float)degi[n]);
}

__global__ __launch_bounds__(512) void col_scan(const int* __restrict__ bh,
                                                int* __restrict__ off,
                                                int* __restrict__ total) {
    __shared__ int sh[512];
    int d = blockIdx.x, t = threadIdx.x;
    int v = (t < P1B) ? bh[t * NDIG + d] : 0;
    sh[t] = v;
    __syncthreads();
#pragma unroll
    for (int o = 1; o < 512; o <<= 1) {
        int x = (t >= o) ? sh[t - o] : 0;
        __syncthreads();
        sh[t] += x;
        __syncthreads();
    }
    if (t < P1B) off[d * P1B + t] = sh[t] - v;   // exclusive
    if (t == 511) total[d] = sh[511];
}

// rows padded to x8 (8-entry pipelined gather loop)
__global__ __launch_bounds__(256) void dig_scan(const int* __restrict__ total,
                                                int* __restrict__ dig_raw,
                                                int* __restrict__ dig_pad) {
    __shared__ int sh[256], sh2[256];
    int t = threadIdx.x;
    int v   = (t < NDIG) ? total[t] : 0;
    int cap = (t < NDIG) ? ((v + 256 * 7 + 7) & ~7) : 0;
    sh[t] = v; sh2[t] = cap;
    __syncthreads();
#pragma unroll
    for (int o = 1; o < 256; o <<= 1) {
        int x = (t >= o) ? sh[t - o] : 0;
        int y = (t >= o) ? sh2[t - o] : 0;
        __syncthreads();
        sh[t] += x; sh2[t] += y;
        __syncthreads();
    }
    if (t < NDIG) { dig_raw[t] = sh[t] - v; dig_pad[t] = sh2[t] - cap; }
}

__global__ __launch_bounds__(256) void pass1_scatter(const int* __restrict__ I,
                                                     const int* __restrict__ J,
                                                     const int* __restrict__ off,
                                                     const int* __restrict__ dig_raw,
                                                     unsigned* __restrict__ ebuf) {
    __shared__ int cnt2[NDIG];
    __shared__ int base[NDIG];
    int t = threadIdx.x, b = blockIdx.x;
    for (int i = t; i < NDIG; i += 256) {
        cnt2[i] = 0;
        base[i] = dig_raw[i] + off[i * P1B + b];
    }
    __syncthreads();
    int e0 = b * EPB;
    int e1 = min(e0 + EPB, N_EDGES);
    for (int e = e0 + t; e < e1; e += 256) {
        int i = I[e], j = J[e];
        int li = atomicAdd(&cnt2[i >> 8], 1);
        ebuf[base[i >> 8] + li] = ((unsigned)i << 16) | (unsigned)j;
        int lj = atomicAdd(&cnt2[j >> 8], 1);
        ebuf[base[j >> 8] + lj] = ((unsigned)j << 16) | (unsigned)i;
    }
}

// pass 2: emits row_start, deg2, padded (other,w) int2 CSR; rows x8-padded;
// pad entries (n, w=0) contribute exactly 0. Slot order within a row is
// arbitrary -> reader may partition slots any way that covers each once.
__global__ __launch_bounds__(256) void pass2_csr(const unsigned* __restrict__ ebuf,
                                                 const int* __restrict__ dig_raw,
                                                 const int* __restrict__ total,
                                                 const int* __restrict__ dig_pad,
                                                 const float* __restrict__ dinv,
                                                 int* __restrict__ row_start,
                                                 int* __restrict__ deg2,
                                                 int2* __restrict__ ent) {
    __shared__ unsigned eb[P2CAP];
    __shared__ int cnt[256], loc[256], cur[256];
    int d = blockIdx.x, t = threadIdx.x;
    int s = dig_raw[d];
    int c = total[d]; if (c > P2CAP) c = P2CAP;
    for (int i = t; i < c; i += 256) eb[i] = ebuf[s + i];
    cnt[t] = 0;
    __syncthreads();
    for (int i = t; i < c; i += 256)
        atomicAdd(&cnt[(eb[i] >> 16) & 255], 1);
    __syncthreads();
    int pc = (cnt[t] + 7) & ~7;
    loc[t] = pc;
    __syncthreads();
#pragma unroll
    for (int o = 1; o < 256; o <<= 1) {
        int x = (t >= o) ? loc[t - o] : 0;
        __syncthreads();
        loc[t] += x;
        __syncthreads();
    }
    int mybase = dig_pad[d] + loc[t] - pc;        // x8-aligned entry index
    int n = (d << 8) + t;
    if (n < N_NODES) {
        row_start[n] = mybase;
        deg2[n] = cnt[t];
    }
    cur[t] = mybase;
    __syncthreads();
    for (int i = t; i < c; i += 256) {
        unsigned v = eb[i];
        int ln = (int)(v >> 16) & 255;
        int other = (int)(v & 0xffffu);
        int p = atomicAdd(&cur[ln], 1);
        float w = dinv[(d << 8) + ln] * dinv[other];
        ent[p] = make_int2(other, __float_as_int(w));
    }
    __syncthreads();
    if (n < N_NODES) {
        for (int p = mybase + cnt[t]; p < mybase + pc; p++)
            ent[p] = make_int2(n, 0);
    }
}

// ---- degree sort (LPT): perm = nodes in descending deg-bucket order ------
__global__ __launch_bounds__(256) void sort_hist(const int* __restrict__ deg2,
                                                 int* __restrict__ sbh) {
    __shared__ int h[SBIN];
    int t = threadIdx.x, b = blockIdx.x;
    if (t < SBIN) h[t] = 0;
    __syncthreads();
    int n = b * 256 + t;
    if (n < N_NODES) atomicAdd(&h[min(deg2[n], 255) >> 3], 1);
    __syncthreads();
    if (t < SBIN) sbh[b * SBIN + t] = h[t];
}

__global__ __launch_bounds__(256) void sort_scan(const int* __restrict__ sbh,
                                                 int* __restrict__ soff,
                                                 int* __restrict__ stot) {
    __shared__ int sh[256];
    int bin = blockIdx.x, t = threadIdx.x;
    int v = (t < NDIG) ? sbh[t * SBIN + bin] : 0;
    sh[t] = v;
    __syncthreads();
#pragma unroll
    for (int o = 1; o < 256; o <<= 1) {
        int x = (t >= o) ? sh[t - o] : 0;
        __syncthreads();
        sh[t] += x;
        __syncthreads();
    }
    if (t < NDIG) soff[bin * NDIG + t] = sh[t] - v;
    if (t == 255) stot[bin] = sh[255];
}

__global__ void sort_base(const int* __restrict__ stot, int* __restrict__ sbase) {
    int t = threadIdx.x;
    if (t < SBIN) {
        int acc = 0;
        for (int b2 = t + 1; b2 < SBIN; b2++) acc += stot[b2];  // descending (LPT)
        sbase[t] = acc;
    }
}

__global__ __launch_bounds__(256) void sort_scatter(const int* __restrict__ deg2,
                                                    const int* __restrict__ soff,
                                                    const int* __restrict__ sbase,
                                                    int* __restrict__ perm) {
    __shared__ int c[SBIN];
    __shared__ int bb[SBIN];
    int t = threadIdx.x, b = blockIdx.x;
    if (t < SBIN) { c[t] = 0; bb[t] = sbase[t] + soff[t * NDIG + b]; }
    __syncthreads();
    int n = b * 256 + t;
    if (n < N_NODES) {
        int bin = min(deg2[n], 255) >> 3;
        int p = atomicAdd(&c[bin], 1);
        perm[bb[bin] + p] = n;
    }
}

// ---- first layer: x = relu(K1 @ xn_in), xn_in is (128, N) f32 ----------
__global__ __launch_bounds__(256) void first_layer(const float* __restrict__ xn,
                                                   const float* __restrict__ k1f,
                                                   float* __restrict__ x_cur,
                                                   float* __restrict__ x_old) {
    __shared__ float Ks[NOPEN * 129];
    __shared__ float xs[32 * 64];
    int t = threadIdx.x;
    int n0 = blockIdx.x * 64;
    for (int idx = t; idx < NOPEN * NNIN; idx += 256)
        Ks[(idx >> 7) * 129 + (idx & 127)] = k1f[idx];

    int tn = t & 15, to = t >> 4;
    float acc[4][4] = {};
    for (int c0 = 0; c0 < NNIN; c0 += 32) {
        __syncthreads();
        for (int idx = t; idx < 32 * 64; idx += 256) {
            int ci = idx >> 6, n = idx & 63;
            int gn = n0 + n;
            xs[ci * 64 + n] = (gn < N_NODES) ? xn[(size_t)(c0 + ci) * N_NODES + gn] : 0.f;
        }
        __syncthreads();
        for (int ci = 0; ci < 32; ci++) {
            float xv[4], kv[4];
#pragma unroll
            for (int i2 = 0; i2 < 4; i2++) xv[i2] = xs[ci * 64 + tn * 4 + i2];
#pragma unroll
            for (int j = 0; j < 4; j++) kv[j] = Ks[(to * 4 + j) * 129 + c0 + ci];
#pragma unroll
            for (int i2 = 0; i2 < 4; i2++)
#pragma unroll
                for (int j = 0; j < 4; j++) acc[i2][j] += xv[i2] * kv[j];
        }
    }
#pragma unroll
    for (int i2 = 0; i2 < 4; i2++) {
        int node = n0 + tn * 4 + i2;
        if (node < N_NODES) {
            float4 st;
            st.x = fmaxf(acc[i2][0], 0.f);
            st.y = fmaxf(acc[i2][1], 0.f);
            st.z = fmaxf(acc[i2][2], 0.f);
            st.w = fmaxf(acc[i2][3], 0.f);
            *(float4*)&x_cur[(size_t)node * 64 + to * 4] = st;
            *(float4*)&x_old[(size_t)node * 64 + to * 4] = st;
        }
    }
}

// ---- Y[n][o] = sum_c K[o][c] * x[n][c], fp16 out (layer 0 only) --------
__global__ __launch_bounds__(256) void mat_y(const float* __restrict__ x,
                                             const float* __restrict__ K,
                                             __half* __restrict__ Y) {
    __shared__ float Ks[64 * 65];
    __shared__ float xs[64 * 65];
    int t = threadIdx.x, n0 = blockIdx.x * 64;
    for (int idx = t; idx < 4096; idx += 256) {
        int r = idx >> 6, c = idx & 63;
        Ks[r * 65 + c] = K[idx];
        int gn = n0 + r;
        xs[r * 65 + c] = (gn < N_NODES) ? x[(size_t)gn * 64 + c] : 0.f;
    }
    __syncthreads();
    int tn = t & 15, to = t >> 4;
    float acc[4][4] = {};
    for (int c = 0; c < 64; c++) {
        float xv[4], kv[4];
#pragma unroll
        for (int i2 = 0; i2 < 4; i2++) xv[i2] = xs[(tn * 4 + i2) * 65 + c];
#pragma unroll
        for (int j = 0; j < 4; j++) kv[j] = Ks[(to * 4 + j) * 65 + c];
#pragma unroll
        for (int i2 = 0; i2 < 4; i2++)
#pragma unroll
            for (int j = 0; j < 4; j++) acc[i2][j] += xv[i2] * kv[j];
    }
#pragma unroll
    for (int i2 = 0; i2 < 4; i2++) {
        int node = n0 + tn * 4 + i2;
        if (node < N_NODES) {
            __half2 h0 = __floats2half2_rn(acc[i2][0], acc[i2][1]);
            __half2 h1 = __floats2half2_rn(acc[i2][2], acc[i2][3]);
            __half2* dst = (__half2*)&Y[(size_t)node * 64 + to * 4];
            dst[0] = h0;
            dst[1] = h1;
        }
    }
}

// ---- fused gather + update + next-layer Y --------------------------------
// 512t/8-wave blocks, degree-sorted perm (LPT), parity-split chunks
// (half0: slots 0-3, half1: slots 4-7), two-deep software pipeline:
// ent prefetched 2 iters ahead, Y gathers (raw __half2) 1 iter ahead.
__global__ __launch_bounds__(512) void gather_update(const __half* __restrict__ Y,
                                                     const float* __restrict__ x_cur,
                                                     const float* __restrict__ x_old,
                                                     const int2* __restrict__ ent,
                                                     const int* __restrict__ row_start,
                                                     const int* __restrict__ deg2,
                                                     const int* __restrict__ perm,
                                                     const float* __restrict__ K,
                                                     const float* __restrict__ Kn,
                                                     float* __restrict__ x_out,
                                                     __half* __restrict__ Y_out) {
    __shared__ float Ks[64 * 66];    // d[c] = sum_o K[c][o] s[o]   at Ks[c*66+o]
    __shared__ float Ksn[64 * 66];   // Y[o] = sum_c Kn[o][c] x[c]  at Ksn[o*66+c]
    __shared__ float Ss[8][64];
    int t = threadIdx.x;
    int wv = t >> 6, lane = t & 63;
    int c2  = lane & 31;             // channel-pair index
    int sel = lane >> 5;             // half-wave id
    int n = __builtin_amdgcn_readfirstlane(perm[blockIdx.x * 8 + wv]);

    // issue per-node meta + state loads first: latency hides under K staging
    int beg = row_start[n];
    int dg  = deg2[n];
    f32x2 yn = h2f(*(const __half2*)&Y[((size_t)n << 6) + 2 * c2]);
    float xc = x_cur[(size_t)n * 64 + lane];
    float xo = x_old[(size_t)n * 64 + lane];

    for (int idx = t; idx < 4096; idx += 512) {
        int r = idx >> 6, cc = idx & 63;
        Ks[r * 66 + cc]  = K[idx];
        Ksn[r * 66 + cc] = Kn[idx];
    }
    __syncthreads();

    beg = __builtin_amdgcn_readfirstlane(beg);   // % 8 == 0
    dg  = __builtin_amdgcn_readfirstlane(dg);
    int end = beg + ((dg + 7) & ~7);             // x8-padded, no tail

    const f32x2 C3v  = {-0.33333334f,  -0.33333334f };
    const f32x2 C5v  = { 0.13333334f,   0.13333334f };
    const f32x2 C7v  = {-0.053968254f, -0.053968254f};
    const f32x2 ONEv = { 1.0f, 1.0f };
    const f32x2 NEG1 = {-1.0f, -1.0f};

    const __half2* Yc2 = (const __half2*)Y;
    int sel4 = sel << 2;             // this half's first slot in each 8-chunk

    // pipeline state: iter i ent (A0,B0) + gathers (G*); iter i+1 ent (A1,B1)
    int4 A0, B0, A1, B1;
    __half2 G0, G1, G2, G3;
    int k = beg;
    if (k < end) {
        A0 = *(const int4*)(ent + k + sel4);
        B0 = *(const int4*)(ent + k + sel4 + 2);
    }
    if (k + 8 < end) {
        A1 = *(const int4*)(ent + k + 8 + sel4);
        B1 = *(const int4*)(ent + k + 8 + sel4 + 2);
    }
    if (k < end) {
        G0 = Yc2[((unsigned)A0.x << 5) + c2];
        G1 = Yc2[((unsigned)A0.z << 5) + c2];
        G2 = Yc2[((unsigned)B0.x << 5) + c2];
        G3 = Yc2[((unsigned)B0.z << 5) + c2];
    }

    f32x2 s = {0.f, 0.f};
#define EDGE_ACC(gh, wbits)                                                 \
        {                                                                   \
            float wf = __int_as_float(wbits);                               \
            f32x2 wvv = {wf, wf};                                           \
            f32x2 dd  = pk_fma(h2f(gh), NEG1, yn);                          \
            f32x2 zz  = pk_mul(wvv, dd);                                    \
            f32x2 z2  = pk_mul(zz, zz);                                     \
            f32x2 pp  = pk_fma(z2, pk_fma(z2, pk_fma(z2, C7v, C5v), C3v), ONEv); \
            s = pk_fma(pk_mul(wvv, zz), pp, s);                             \
        }
    for (; k < end; k += 8) {
        // prefetch ent for iter i+2 (scalar addr, no deps)
        int4 A2, B2;
        if (k + 16 < end) {
            A2 = *(const int4*)(ent + k + 16 + sel4);
            B2 = *(const int4*)(ent + k + 16 + sel4 + 2);
        }
        // issue gathers for iter i+1 (A1/B1 loaded one iter ago)
        __half2 P0, P1, P2, P3;
        if (k + 8 < end) {
            P0 = Yc2[((unsigned)A1.x << 5) + c2];
            P1 = Yc2[((unsigned)A1.z << 5) + c2];
            P2 = Yc2[((unsigned)B1.x << 5) + c2];
            P3 = Yc2[((unsigned)B1.z << 5) + c2];
        }
        // compute iter i (G* issued one iter ago)
        EDGE_ACC(G0, A0.y)
        EDGE_ACC(G1, A0.w)
        EDGE_ACC(G2, B0.y)
        EDGE_ACC(G3, B0.w)
        // rotate
        A0 = A1; B0 = B1; A1 = A2; B1 = B2;
        G0 = P0; G1 = P1; G2 = P2; G3 = P3;
    }
#undef EDGE_ACC

    s.x += __shfl_xor(s.x, 32, 64);
    s.y += __shfl_xor(s.y, 32, 64);
    if (lane < 32) *(f32x2*)&Ss[wv][2 * c2] = s;   // in-wave LDS ordering

    f32x2 acc2 = {0.f, 0.f};
#pragma unroll
    for (int o = 0; o < 64; o += 2)
        acc2 = pk_fma(*(const f32x2*)&Ks[lane * 66 + o],
                      *(const f32x2*)&Ss[wv][o], acc2);
    float xnew = 2.f * xc - xo - HSQ * (acc2.x + acc2.y);
    __builtin_nontemporal_store(xnew, &x_out[(size_t)n * 64 + lane]);
    Ss[wv][lane] = xnew;
    f32x2 acc3 = {0.f, 0.f};
#pragma unroll
    for (int c = 0; c < 64; c += 2)
        acc3 = pk_fma(*(const f32x2*)&Ksn[lane * 66 + c],
                      *(const f32x2*)&Ss[wv][c], acc3);
    Y_out[((size_t)n << 6) + lane] = __float2half(acc3.x + acc3.y);
}

// ---- out[n][o] = sum_c KNc[o][c] * x[n][c]; out is (N,40) f32 ----------
__global__ __launch_bounds__(256) void out_kernel(const float* __restrict__ x,
                                                  const float* __restrict__ Kc,
                                                  float* __restrict__ out) {
    __shared__ float xs[64 * 65];
    __shared__ float Ks[40 * 65];
    int t = threadIdx.x, n0 = blockIdx.x * 64;
    for (int idx = t; idx < 4096; idx += 256) {
        int r = idx >> 6, c = idx & 63;
        int gn = n0 + r;
        xs[r * 65 + c] = (gn < N_NODES) ? x[(size_t)gn * 64 + c] : 0.f;
    }
    for (int idx = t; idx < NUM_OUT * 64; idx += 256) {
        int r = idx >> 6, c = idx & 63;
        Ks[r * 65 + c] = Kc[idx];
    }
    __syncthreads();
    if (t < 160) {
        int tn = t & 15, to = t >> 4;
        float acc[4][4] = {};
        for (int c = 0; c < 64; c++) {
            float xv[4], kv[4];
#pragma unroll
            for (int i2 = 0; i2 < 4; i2++) xv[i2] = xs[(tn * 4 + i2) * 65 + c];
#pragma unroll
            for (int j = 0; j < 4; j++) kv[j] = Ks[(to * 4 + j) * 65 + c];
#pragma unroll
            for (int i2 = 0; i2 < 4; i2++)
#pragma unroll
                for (int j = 0; j < 4; j++) acc[i2][j] += xv[i2] * kv[j];
        }
#pragma unroll
        for (int i2 = 0; i2 < 4; i2++) {
            int node = n0 + tn * 4 + i2;
            if (node < N_NODES) {
#pragma unroll
                for (int j = 0; j < 4; j++)
                    out[(size_t)node * NUM_OUT + to * 4 + j] = acc[i2][j];
            }
        }
    }
}

extern "C" void kernel_launch(void* const* d_in, const int* in_sizes, int n_in,
                              void* d_out, int out_size, void* d_ws, size_t ws_size,
                              hipStream_t stream) {
    const float* xn = (const float*)d_in[0];
    const int*   I  = (const int*)d_in[1];
    const int*   J  = (const int*)d_in[2];
    const float* K1 = (const float*)d_in[4];
    const float* K2 = (const float*)d_in[5];
    const float* Kc = (const float*)d_in[6];

    const size_t NC = (size_t)N_NODES * NOPEN;  // 3.2M
    float*    f       = (float*)d_ws;
    float*    x_cur   = f;
    float*    x_old   = f + NC;
    __half*   Y0      = (__half*)(f + 2 * NC);
    __half*   Y1      = (__half*)(f + 2 * NC + NC / 2);
    float*    dinv    = f + 3 * NC;
    int*      degi    = (int*)(dinv + N_NODES);
    int*      deg2    = degi + N_NODES;
    int*      row_st  = deg2 + N_NODES;
    int*      total   = row_st + N_NODES;          // 256
    int*      dig_raw = total + 256;               // 256
    int*      dig_pad = dig_raw + 256;             // 256
    int*      bh      = dig_pad + 256;             // P1B*NDIG = 76636
    int*      off     = bh + 80000;                // NDIG*P1B = 76636
    int*      perm    = off + 80000;               // 50048
    int*      sbh     = perm + 50048;              // 196*32 -> 6400
    int*      soff    = sbh + 6400;                // 32*196 -> 6400
    int*      stot    = soff + 6400;               // 64
    int*      sbase   = stot + 64;                 // 64
    unsigned* ebuf    = (unsigned*)(sbase + 64);   // 1.6M u32
    int2*     ent     = (int2*)(ebuf + 2 * (size_t)N_EDGES);  // ~1.96M int2 (~16MB)

    dim3 B(256);
    const int GN = (N_NODES + 255) / 256;   // 196

    deg_init<<<GN, B, 0, stream>>>(degi);
    count_all<<<P1B, B, 0, stream>>>(I, J, degi, bh);
    calc_dinv<<<GN, B, 0, stream>>>(degi, dinv);
    col_scan<<<NDIG, dim3(512), 0, stream>>>(bh, off, total);
    dig_scan<<<1, B, 0, stream>>>(total, dig_raw, dig_pad);
    pass1_scatter<<<P1B, B, 0, stream>>>(I, J, off, dig_raw, ebuf);
    pass2_csr<<<NDIG, B, 0, stream>>>(ebuf, dig_raw, total, dig_pad, dinv, row_st, deg2, ent);

    // degree sort (LPT): 4 tiny kernels, atomic-free globally
    sort_hist<<<NDIG, B, 0, stream>>>(deg2, sbh);
    sort_scan<<<SBIN, B, 0, stream>>>(sbh, soff, stot);
    sort_base<<<1, dim3(64), 0, stream>>>(stot, sbase);
    sort_scatter<<<NDIG, B, 0, stream>>>(deg2, soff, sbase, perm);

    const int NB = (N_NODES + 63) / 64;     // 782
    first_layer<<<NB, B, 0, stream>>>(xn, K1, x_cur, x_old);
    mat_y<<<NB, B, 0, stream>>>(x_cur, K2, Y0);   // Y for layer 0 only

    __half* Yin = Y0;
    __half* Yout = Y1;
    float* xc = x_cur;
    float* xo = x_old;
    for (int l = 0; l < NLAYER; l++) {
        const float* Kl = K2 + l * NOPEN * NOPEN;
        const float* Knext = K2 + (l + 1 < NLAYER ? l + 1 : l) * NOPEN * NOPEN;
        gather_update<<<N_NODES / 8, dim3(512), 0, stream>>>(
            Yin, xc, xo, ent, row_st, deg2, perm, Kl, Knext, xo, Yout);
        float* tmp = xc; xc = xo; xo = tmp;
        __half* th = Yin; Yin = Yout; Yout = th;
    }
    out_kernel<<<NB, B, 0, stream>>>(xc, Kc, (float*)d_out);
}